// Round 3
// baseline (428.140 us; speedup 1.0000x reference)
//
#include <hip/hip_runtime.h>

#define N_COLS 8192

typedef float floatx4 __attribute__((ext_vector_type(4)));

// Kernel 1: single block, 1024 threads. Max-reduce x[0:8192], then write a
// dense float mask[8192] (1.0f where floor((x/max)*255) == t, else 0.0f) into
// workspace. Bit-exact div->mul->floorf chain (same as the verified kernels).
__global__ __launch_bounds__(1024) void spike_mask_kernel(const float* __restrict__ x,
                                                          const int* __restrict__ t_ptr,
                                                          float* __restrict__ mask) {
    __shared__ float smax[16];
    __shared__ float s_maxv;
    const int tid = threadIdx.x;  // 0..1023

    float vals[8];
    float m = -1e30f;
#pragma unroll
    for (int j = 0; j < 8; ++j) {
        vals[j] = x[tid + j * 1024];
        m = fmaxf(m, vals[j]);
    }
#pragma unroll
    for (int off = 32; off > 0; off >>= 1)
        m = fmaxf(m, __shfl_down(m, off, 64));
    if ((tid & 63) == 0) smax[tid >> 6] = m;
    __syncthreads();
    if (tid < 16) {
        float mm = smax[tid];
#pragma unroll
        for (int off = 8; off > 0; off >>= 1)
            mm = fmaxf(mm, __shfl_down(mm, off, 16));
        if (tid == 0) s_maxv = mm;
    }
    __syncthreads();

    const float maxv = s_maxv;
    const int t = *t_ptr;
#pragma unroll
    for (int j = 0; j < 8; ++j) {
        const int q = (int)floorf((vals[j] / maxv) * 255.0f);
        mask[tid + j * 1024] = (q == t) ? 1.0f : 0.0f;
    }
}

// Kernel 2: pure streaming writer. Grid = 2048 blocks x 256 threads:
//   blockIdx & 7   -> 1024-column tile (8 tiles cover 8192 cols)
//   blockIdx >> 3  -> 32-row tile      (256 tiles cover 8192 rows)
// Each thread owns 4 consecutive columns: one float4 mask load (L2-hit),
// then 32 rows of nontemporal float4 stores. Weight is only fetched for the
// ~0.4% of lanes whose 4-column group contains a spike (exec-masked loads).
// No reduction, no barrier, no LDS -> stores start issuing immediately.
__global__ __launch_bounds__(256) void stream_write_kernel(const float* __restrict__ w,
                                                           const float* __restrict__ mask,
                                                           float* __restrict__ out) {
    const int tid = threadIdx.x;                   // 0..255
    const int g = ((blockIdx.x & 7) << 8) + tid;   // float4 group index 0..2047
    const int r0 = (blockIdx.x >> 3) << 5;         // first row of this tile

    const floatx4 mv = ((const floatx4*)mask)[g];
    const bool any = (mv.x != 0.0f) | (mv.y != 0.0f) | (mv.z != 0.0f) | (mv.w != 0.0f);

    const floatx4* __restrict__ w4 = (const floatx4*)w;
    floatx4* __restrict__ o4 = (floatx4*)out;
    size_t idx4 = ((size_t)r0 << 11) + (size_t)g;  // float4 units: r*2048 + g

    if (any) {
        // rare path: weight read + mask multiply (mask is exactly 0.0/1.0)
#pragma unroll 8
        for (int r = 0; r < 32; ++r) {
            const floatx4 wv = w4[idx4];
            floatx4 ov = wv * mv;
            __builtin_nontemporal_store(ov, &o4[idx4]);
            idx4 += (N_COLS >> 2);
        }
    } else {
        const floatx4 z = {0.0f, 0.0f, 0.0f, 0.0f};
#pragma unroll 8
        for (int r = 0; r < 32; ++r) {
            __builtin_nontemporal_store(z, &o4[idx4]);
            idx4 += (N_COLS >> 2);
        }
    }
}

extern "C" void kernel_launch(void* const* d_in, const int* in_sizes, int n_in,
                              void* d_out, int out_size, void* d_ws, size_t ws_size,
                              hipStream_t stream) {
    const float* x = (const float*)d_in[0];   // [1, 8192] fp32
    const float* w = (const float*)d_in[1];   // [8192, 8192] fp32
    const int* t = (const int*)d_in[2];       // scalar int
    float* out = (float*)d_out;               // [8192, 8192] fp32
    float* mask = (float*)d_ws;               // [8192] fp32 spike mask

    // 1) Tiny: build the spike mask (one block, ~5 us).
    spike_mask_kernel<<<1, 1024, 0, stream>>>(x, t, mask);

    // 2) Stream the full output: zeros everywhere, weight on spike columns.
    stream_write_kernel<<<2048, 256, 0, stream>>>(w, mask, out);
}

// Round 4
// 390.141 us; speedup vs baseline: 1.0974x; 1.0974x over previous
//
#include <hip/hip_runtime.h>

#define N_COLS 8192
#define LOG2_COLS 13

// Kernel 1: single block. Max-reduce over x[0:8192], build spike mask, and
// COMPACT the spike column indices into d_ws: meta[0]=count, meta[1..]=cols.
// Exact IEEE div -> mul -> floorf bit-matches the numpy reference.
__global__ __launch_bounds__(1024) void spike_kernel(const float* __restrict__ x,
                                                     const int* __restrict__ t_ptr,
                                                     int* __restrict__ meta) {
    __shared__ float smax[16];
    __shared__ float s_maxv;
    __shared__ int s_count;
    const int tid = threadIdx.x;  // 0..1023

    if (tid == 0) s_count = 0;

    float vals[8];
    float m = -1e30f;
#pragma unroll
    for (int j = 0; j < 8; ++j) {
        vals[j] = x[tid + j * 1024];
        m = fmaxf(m, vals[j]);
    }
#pragma unroll
    for (int off = 32; off > 0; off >>= 1)
        m = fmaxf(m, __shfl_down(m, off, 64));
    if ((tid & 63) == 0) smax[tid >> 6] = m;
    __syncthreads();
    if (tid < 16) {
        float mm = smax[tid];
#pragma unroll
        for (int off = 8; off > 0; off >>= 1)
            mm = fmaxf(mm, __shfl_down(mm, off, 16));
        if (tid == 0) s_maxv = mm;
    }
    __syncthreads();

    const float maxv = s_maxv;
    const int t = *t_ptr;
#pragma unroll
    for (int j = 0; j < 8; ++j) {
        const int q = (int)floorf((vals[j] / maxv) * 255.0f);
        if (q == t) {
            const int slot = atomicAdd(&s_count, 1);
            meta[1 + slot] = tid + j * 1024;   // column index
        }
    }
    __syncthreads();
    if (tid == 0) meta[0] = s_count;
}

// Kernel 2: after d_out has been zeroed, copy weight[:,c] -> out[:,c] for each
// compacted spike column c. Grid-stride; handles any count 0..8192. The writes
// are inherently scattered (4 B elements at 32 KiB row stride) but total true
// traffic is only ~17 MB of 64 B lines for the expected ~32 spike columns —
// latency-bound, fully parallel across 524288 threads.
__global__ __launch_bounds__(256) void scatter_kernel(const float* __restrict__ w,
                                                      const int* __restrict__ meta,
                                                      float* __restrict__ out) {
    const int count = meta[0];
    const int* cols = meta + 1;
    const long total = (long)count << LOG2_COLS;          // count * 8192 rows
    const long stride = (long)gridDim.x * blockDim.x;
    for (long idx = (long)blockIdx.x * blockDim.x + threadIdx.x; idx < total;
         idx += stride) {
        const int k = (int)(idx >> LOG2_COLS);            // spike-list index
        const int r = (int)(idx & (N_COLS - 1));          // row
        const long off = ((long)r << LOG2_COLS) + cols[k];
        out[off] = w[off];                                 // spike==1.0 exactly
    }
}

extern "C" void kernel_launch(void* const* d_in, const int* in_sizes, int n_in,
                              void* d_out, int out_size, void* d_ws, size_t ws_size,
                              hipStream_t stream) {
    const float* x = (const float*)d_in[0];   // [1, 8192] fp32
    const float* w = (const float*)d_in[1];   // [8192, 8192] fp32
    const int* t = (const int*)d_in[2];       // scalar int
    float* out = (float*)d_out;               // [8192, 8192] fp32
    int* meta = (int*)d_ws;                   // [0]=count, [1..8192]=cols

    // 1) Build compacted spike-column list (tiny, 1 block).
    spike_kernel<<<1, 1024, 0, stream>>>(x, t, meta);

    // 2) Zero the output via the fast rocclr fill path (~6.4 TB/s).
    //    out_size is ALREADY IN BYTES (round-0 profile: fill WRITE_SIZE was
    //    4x the 256 MiB output when multiplied by sizeof(float)).
    hipMemsetAsync(out, 0, (size_t)out_size, stream);

    // 3) Overwrite only the spike columns with weight values.
    scatter_kernel<<<2048, 256, 0, stream>>>(w, meta, out);
}